// Round 3
// baseline (1259.865 us; speedup 1.0000x reference)
//
#include <hip/hip_runtime.h>

#define NNODES 100000
#define NMP 3
#define NEDGES 1000000
#define D 64
#define NTOT (NMP * NNODES)          // 300000
#define BINW 512                     // destination nodes per bin
#define BSH 9                        // log2(BINW)
#define NBIN 586                     // ceil(NTOT / BINW)
#define CAPB 5632                    // slots per bin segment (lambda=5120, +7 sigma)
#define T1 3072                      // edges per split block
#define OVCAP 131072                 // overflow entries (12 B each)

typedef __attribute__((ext_vector_type(8))) short bf16x8;
typedef __attribute__((ext_vector_type(4))) float floatx4;

__device__ __forceinline__ unsigned short f2bf(float f) {
    unsigned u = __float_as_uint(f);
    u = (u + 0x7FFFu + ((u >> 16) & 1u)) >> 16;   // RNE
    return (unsigned short)u;
}
__device__ __forceinline__ float bf2f_lo(unsigned u) { return __uint_as_float(u << 16); }
__device__ __forceinline__ float bf2f_hi(unsigned u) { return __uint_as_float(u & 0xFFFF0000u); }

// native ds_add_f32 (fire-and-forget). Default atomicAdd(float*) on LDS lowers to a CAS
// loop (~2 dependent LDS round-trips/lane) -- that was round-1's 1082us disaster.
// Relaxed + workgroup scope lets the compiler emit the native LDS fp-add instruction.
__device__ __forceinline__ void lds_fadd(float* p, float v) {
    __hip_atomic_fetch_add(p, v, __ATOMIC_RELAXED, __HIP_MEMORY_SCOPE_WORKGROUP);
}

// ---------------- split: multisplit into 586 bins, direct scatter ----------------
__global__ __launch_bounds__(512) void split_kernel(const int* __restrict__ ei,
                                                    const float* __restrict__ ew,
                                                    int* __restrict__ gcur,
                                                    int* __restrict__ ovcur,
                                                    int* __restrict__ ovf,
                                                    uint2* __restrict__ A) {
    __shared__ int hist[NBIN], cur[NBIN];
    const int t = threadIdx.x;
    const int mp = blockIdx.y;
    const int e0 = blockIdx.x * T1;
    for (int i = t; i < NBIN; i += 512) hist[i] = 0;
    __syncthreads();
    unsigned key[6]; float w[6]; int bn[6];
#pragma unroll
    for (int i = 0; i < 6; ++i) {
        int e = e0 + i * 512 + t;
        bn[i] = -1;
        if (e < NEDGES) {
            int r = ei[(mp * 2 + 0) * NEDGES + e];
            int c = ei[(mp * 2 + 1) * NEDGES + e];
            w[i] = ew[mp * NEDGES + e];
            int cflat = mp * NNODES + c;
            int rflat = mp * NNODES + r;
            int b = cflat >> BSH;
            bn[i] = b;
            key[i] = ((unsigned)(cflat & (BINW - 1)) << 19) | (unsigned)rflat;
            atomicAdd(&hist[b], 1);
        }
    }
    __syncthreads();
    for (int i = t; i < NBIN; i += 512) {
        int v = hist[i];
        cur[i] = v ? atomicAdd(&gcur[i], v) : 0;   // global space reservation
    }
    __syncthreads();
#pragma unroll
    for (int i = 0; i < 6; ++i) {
        if (bn[i] >= 0) {
            int pos = atomicAdd(&cur[bn[i]], 1);
            if (pos < CAPB) {
                A[(size_t)bn[i] * CAPB + pos] = make_uint2(key[i], __float_as_uint(w[i]));
            } else {                               // correctness valve (~never)
                int op = atomicAdd(ovcur, 1);
                if (op < OVCAP) {
                    int cflat = (bn[i] << BSH) | (int)(key[i] >> 19);
                    ovf[3 * op] = cflat;
                    ovf[3 * op + 1] = (int)(key[i] & 0x7FFFFu);
                    ovf[3 * op + 2] = __float_as_int(w[i]);
                }
            }
        }
    }
}

// ---------------- deg: per-bin weighted in-degree -> dinv ----------------
__global__ __launch_bounds__(256) void deg_kernel(const int* __restrict__ gcur,
                                                  const uint2* __restrict__ A,
                                                  const int* __restrict__ ovcur,
                                                  const int* __restrict__ ovf,
                                                  float* __restrict__ dinv) {
    const int bin = blockIdx.x;
    __shared__ float wsum[BINW];
    const int t = threadIdx.x;
    for (int i = t; i < BINW; i += 256) wsum[i] = 0.0f;
    __syncthreads();
    const int len = min(gcur[bin], CAPB);
    const uint2* Ab = A + (size_t)bin * CAPB;
    for (int p = t; p < len; p += 256) {
        uint2 rec = Ab[p];
        lds_fadd(&wsum[rec.x >> 19], __uint_as_float(rec.y));
    }
    const int ovn = min(*ovcur, OVCAP);
    for (int i = t; i < ovn; i += 256) {
        int cflat = ovf[3 * i];
        if ((cflat >> BSH) == bin)
            lds_fadd(&wsum[cflat & (BINW - 1)], __int_as_float(ovf[3 * i + 2]));
    }
    __syncthreads();
    for (int n = t; n < BINW; n += 256) {
        int nf = bin * BINW + n;
        if (nf < NTOT) {
            float dg = wsum[n];
            dinv[nf] = (dg > 0.0f) ? rsqrtf(dg) : 0.0f;
        }
    }
}

// ---------------- prep: W fp32 [mp][k][n] -> bf16 transposed wT [mp][n][k] ----------------
__global__ __launch_bounds__(256) void prep_w_kernel(const float* __restrict__ W,
                                                     unsigned short* __restrict__ wT) {
    int idx = blockIdx.x * 256 + threadIdx.x;
    if (idx >= NMP * D * D) return;
    int mp = idx >> 12, rem = idx & 4095;
    int k = rem >> 6, n = rem & 63;
    wT[(mp * D + n) * D + k] = f2bf(W[idx]);
}

// ---------------- MFMA GEMM (operand-swapped), dinv[row] folded into h ----------------
__global__ __launch_bounds__(256) void gemm_kernel(const float* __restrict__ x,
                                                   const unsigned short* __restrict__ wT,
                                                   const float* __restrict__ dinv,
                                                   unsigned short* __restrict__ h) {
    const int wave = threadIdx.x >> 6;
    const int lane = threadIdx.x & 63;
    const int rowbase = (blockIdx.x * 4 + wave) * 16;
    if (rowbase >= NNODES) return;
    const int m = lane & 15;
    const int q = lane >> 4;
    const float4* xr = (const float4*)(x + (size_t)(rowbase + m) * D);
    bf16x8 a[2];
#pragma unroll
    for (int kc = 0; kc < 2; ++kc) {
        float4 x0 = xr[kc * 8 + q * 2];
        float4 x1 = xr[kc * 8 + q * 2 + 1];
        a[kc][0] = f2bf(x0.x); a[kc][1] = f2bf(x0.y);
        a[kc][2] = f2bf(x0.z); a[kc][3] = f2bf(x0.w);
        a[kc][4] = f2bf(x1.x); a[kc][5] = f2bf(x1.y);
        a[kc][6] = f2bf(x1.z); a[kc][7] = f2bf(x1.w);
    }
#pragma unroll
    for (int mp = 0; mp < NMP; ++mp) {
        float dv = dinv[mp * NNODES + rowbase + m];   // per x-row scale
#pragma unroll
        for (int nt = 0; nt < 4; ++nt) {
            const bf16x8* bp = (const bf16x8*)(wT + (size_t)(mp * D + nt * 16 + m) * D);
            bf16x8 b0 = bp[q];       // k = q*8 .. +7
            bf16x8 b1 = bp[4 + q];   // k = 32 + q*8 .. +7
            floatx4 acc = {0.f, 0.f, 0.f, 0.f};
            acc = __builtin_amdgcn_mfma_f32_16x16x32_bf16(b0, a[0], acc, 0, 0, 0);
            acc = __builtin_amdgcn_mfma_f32_16x16x32_bf16(b1, a[1], acc, 0, 0, 0);
            unsigned v0 = (unsigned)f2bf(acc[0] * dv) | ((unsigned)f2bf(acc[1] * dv) << 16);
            unsigned v1 = (unsigned)f2bf(acc[2] * dv) | ((unsigned)f2bf(acc[3] * dv) << 16);
            *(uint2*)(h + ((size_t)mp * NNODES + rowbase + m) * D + nt * 16 + q * 4) =
                make_uint2(v0, v1);
        }
    }
}

// ---------------- aggregate: per (bin x feature-half) LDS scatter-accumulate ----------------
// Consumes UNSORTED bin records directly (no CSR). 16 records/wave/iter, depth-2 pipeline.
// LDS layout rotated by node: word(n, f) = n*32 + ((f + n) & 31) -> ~2-way banks (free).
__global__ __launch_bounds__(512) void aggregate_kernel(const int* __restrict__ gcur,
                                                        const uint2* __restrict__ A,
                                                        const int* __restrict__ ovcur,
                                                        const int* __restrict__ ovf,
                                                        const unsigned short* __restrict__ h,
                                                        const float* __restrict__ dinv,
                                                        float* __restrict__ out) {
    const int bin = blockIdx.x >> 1;
    const int fh = blockIdx.x & 1;                 // feature half: feats [fh*32, fh*32+32)
    __shared__ float acc[BINW * 32];               // 64 KB
    const int t = threadIdx.x;
    for (int i = t; i < BINW * 32; i += 512) acc[i] = 0.0f;
    __syncthreads();
    const int len = min(gcur[bin], CAPB);
    const uint2* Ab = A + (size_t)bin * CAPB;
    const uint4* hp = (const uint4*)h;             // h row = 8 uint4 (128 B)
    const int lane = t & 63;
    const int wv = t >> 6;                         // 8 waves
    const int s = lane >> 2;                       // record slot 0..15
    const int c = lane & 3;                        // 16B chunk within 64B half-row
    const int hsel = fh * 4 + c;
    const int i0 = wv * 16 + s;                    // 128 records per block-iter

    uint2 rA = (i0 < len) ? Ab[i0] : make_uint2(0u, 0u);
    uint2 rB = (i0 + 128 < len) ? Ab[i0 + 128] : make_uint2(0u, 0u);
    uint4 hA = hp[(size_t)(rA.x & 0x7FFFFu) * 8 + hsel];
    const int nit = (len + 127) >> 7;
    for (int ib = 0; ib < nit; ++ib) {
        int inx = i0 + (ib + 2) * 128;
        uint2 rC = (inx < len) ? Ab[inx] : make_uint2(0u, 0u);
        uint4 hB = hp[(size_t)(rB.x & 0x7FFFFu) * 8 + hsel];   // addr ready (loaded last iter)
        float w = __uint_as_float(rA.y);           // invalid slots carry w = 0
        int local = (int)(rA.x >> 19);
        int p = local << 5;
        int r0 = (c * 8 + local) & 31;             // rotated base for fl = c*8
        float f0 = bf2f_lo(hA.x), f1 = bf2f_hi(hA.x);
        float f2 = bf2f_lo(hA.y), f3 = bf2f_hi(hA.y);
        float f4 = bf2f_lo(hA.z), f5 = bf2f_hi(hA.z);
        float f6 = bf2f_lo(hA.w), f7 = bf2f_hi(hA.w);
        lds_fadd(&acc[p + ((r0 + 0) & 31)], w * f0);
        lds_fadd(&acc[p + ((r0 + 1) & 31)], w * f1);
        lds_fadd(&acc[p + ((r0 + 2) & 31)], w * f2);
        lds_fadd(&acc[p + ((r0 + 3) & 31)], w * f3);
        lds_fadd(&acc[p + ((r0 + 4) & 31)], w * f4);
        lds_fadd(&acc[p + ((r0 + 5) & 31)], w * f5);
        lds_fadd(&acc[p + ((r0 + 6) & 31)], w * f6);
        lds_fadd(&acc[p + ((r0 + 7) & 31)], w * f7);
        rA = rB; hA = hB; rB = rC;
    }
    // overflow valve (~never executes)
    const int ovn = min(*ovcur, OVCAP);
    for (int i = t; i < ovn; i += 512) {
        int cflat = ovf[3 * i];
        if ((cflat >> BSH) == bin) {
            int local = cflat & (BINW - 1);
            int rf = ovf[3 * i + 1];
            float w = __int_as_float(ovf[3 * i + 2]);
            for (int j = 0; j < 32; ++j) {
                float hv = __uint_as_float((unsigned)h[(size_t)rf * D + fh * 32 + j] << 16);
                lds_fadd(&acc[(local << 5) + ((j + local) & 31)], w * hv);
            }
        }
    }
    __syncthreads();
    // epilogue: unrotate, * dinv[c], relu, 128B-contiguous per node
    const int nn0 = lane >> 3;                     // node within 8-node group
    const int q = lane & 7;                        // 16B chunk of 128B half-row
    for (int nb = wv * 8; nb < BINW; nb += 64) {
        int n = nb + nn0;
        int nf = bin * BINW + n;
        if (nf < NTOT) {
            float dv = dinv[nf];
            int p = n << 5;
            int rb = q * 4 + n;
            float4 o;
            o.x = fmaxf(acc[p + ((rb + 0) & 31)] * dv, 0.0f);
            o.y = fmaxf(acc[p + ((rb + 1) & 31)] * dv, 0.0f);
            o.z = fmaxf(acc[p + ((rb + 2) & 31)] * dv, 0.0f);
            o.w = fmaxf(acc[p + ((rb + 3) & 31)] * dv, 0.0f);
            ((float4*)out)[(size_t)nf * 16 + fh * 8 + q] = o;
        }
    }
}

extern "C" void kernel_launch(void* const* d_in, const int* in_sizes, int n_in,
                              void* d_out, int out_size, void* d_ws, size_t ws_size,
                              hipStream_t stream) {
    const float* x  = (const float*)d_in[0];   // [N, 64]
    const float* W  = (const float*)d_in[1];   // [3, 64, 64]
    const int*   ei = (const int*)d_in[2];     // [3, 2, E]
    const float* ew = (const float*)d_in[3];   // [3, E]
    float* out = (float*)d_out;                // [3, N, 64]

    // layout (bytes); A is live through aggregate so no overlay with h.
    char* ws = (char*)d_ws;
    uint2* A           = (uint2*)(ws + 0);                     // 586*5632*8 = 26,402,816 B
    unsigned short* h  = (unsigned short*)(ws + 26402816);     // 38,400,000 B
    float* dinv        = (float*)(ws + 64802816);              // 1,200,000 B
    unsigned short* wT = (unsigned short*)(ws + 66002816);     // 24,576 B
    int*   gcur        = (int*)(ws + 66027392);                // 2,344 B
    int*   ovcur       = (int*)(ws + 66029736);                // 4 B
    int*   ovf         = (int*)(ws + 66029740);                // 1,572,864 B -> ends ~67.6 MB

    hipMemsetAsync(gcur, 0, 2348, stream);     // gcur + ovcur

    split_kernel<<<dim3((NEDGES + T1 - 1) / T1, NMP), 512, 0, stream>>>(ei, ew, gcur,
                                                                        ovcur, ovf, A);
    deg_kernel<<<NBIN, 256, 0, stream>>>(gcur, A, ovcur, ovf, dinv);
    prep_w_kernel<<<(NMP * D * D + 255) / 256, 256, 0, stream>>>(W, wT);
    gemm_kernel<<<(NNODES / 16 + 3) / 4, 256, 0, stream>>>(x, wT, dinv, h);
    aggregate_kernel<<<NBIN * 2, 512, 0, stream>>>(gcur, A, ovcur, ovf, h, dinv, out);
}

// Round 4
// 286.874 us; speedup vs baseline: 4.3917x; 4.3917x over previous
//
#include <hip/hip_runtime.h>

#define NNODES 100000
#define NMP 3
#define NEDGES 1000000
#define D 64
#define NTOT (NMP * NNODES)          // 300000
#define BINW 1024                    // destination nodes per bin
#define NBIN 293                     // ceil(NTOT / BINW)
#define CAPB 10944                   // slots per bin segment (lambda=10240, +7 sigma)
#define T1 3072                      // edges per split block
#define OVCAP 131072                 // overflow entries (12 B each)

typedef __attribute__((ext_vector_type(8))) short bf16x8;
typedef __attribute__((ext_vector_type(4))) float floatx4;

__device__ __forceinline__ unsigned short f2bf(float f) {
    unsigned u = __float_as_uint(f);
    u = (u + 0x7FFFu + ((u >> 16) & 1u)) >> 16;   // RNE
    return (unsigned short)u;
}
__device__ __forceinline__ float bf2f_lo(unsigned u) { return __uint_as_float(u << 16); }
__device__ __forceinline__ float bf2f_hi(unsigned u) { return __uint_as_float(u & 0xFFFF0000u); }

// ---------------- split: multisplit into 293 bins, direct scatter (no LDS reorder) ----------------
__global__ __launch_bounds__(512) void split_kernel(const int* __restrict__ ei,
                                                    const float* __restrict__ ew,
                                                    int* __restrict__ gcur,
                                                    int* __restrict__ ovcur,
                                                    int* __restrict__ ovf,
                                                    uint2* __restrict__ A) {
    __shared__ int hist[NBIN], cur[NBIN];
    const int t = threadIdx.x;
    const int mp = blockIdx.y;
    const int e0 = blockIdx.x * T1;
    for (int i = t; i < NBIN; i += 512) hist[i] = 0;
    __syncthreads();
    unsigned key[6]; float w[6]; int bn[6];
#pragma unroll
    for (int i = 0; i < 6; ++i) {
        int e = e0 + i * 512 + t;
        bn[i] = -1;
        if (e < NEDGES) {
            int r = ei[(mp * 2 + 0) * NEDGES + e];
            int c = ei[(mp * 2 + 1) * NEDGES + e];
            w[i] = ew[mp * NEDGES + e];
            int cflat = mp * NNODES + c;
            int rflat = mp * NNODES + r;
            int b = cflat >> 10;
            bn[i] = b;
            key[i] = ((unsigned)(cflat & 1023) << 19) | (unsigned)rflat;
            atomicAdd(&hist[b], 1);
        }
    }
    __syncthreads();
    for (int i = t; i < NBIN; i += 512) {
        int v = hist[i];
        cur[i] = v ? atomicAdd(&gcur[i], v) : 0;   // global space reservation -> running cursor
    }
    __syncthreads();
#pragma unroll
    for (int i = 0; i < 6; ++i) {
        if (bn[i] >= 0) {
            int pos = atomicAdd(&cur[bn[i]], 1);
            if (pos < CAPB) {
                A[(size_t)bn[i] * CAPB + pos] = make_uint2(key[i], __float_as_uint(w[i]));
            } else {                               // correctness valve (~never)
                int op = atomicAdd(ovcur, 1);
                if (op < OVCAP) {
                    int cflat = (bn[i] << 10) | (int)(key[i] >> 19);
                    ovf[3 * op] = cflat;
                    ovf[3 * op + 1] = (int)(key[i] & 0x7FFFFu);
                    ovf[3 * op + 2] = __float_as_int(w[i]);
                }
            }
        }
    }
}

// ---------------- compact2: per 1024-node bin -> per-node CSR {rflat, ew}; dinv ----------------
__global__ __launch_bounds__(256) void compact2_kernel(const int* __restrict__ gcur,
                                                       const uint2* __restrict__ A,
                                                       const int* __restrict__ ovcur,
                                                       const int* __restrict__ ovf,
                                                       uint2* __restrict__ C,
                                                       int2* __restrict__ nodeoff,
                                                       float* __restrict__ dinv) {
    const int bin = blockIdx.x;
    __shared__ int cnt[BINW];
    __shared__ float wsum[BINW];
    __shared__ int pos[BINW];
    __shared__ int sh[256];
    const int t = threadIdx.x;
    for (int i = t; i < BINW; i += 256) { cnt[i] = 0; wsum[i] = 0.0f; }
    __syncthreads();
    const int len = min(gcur[bin], CAPB);
    const uint2* Ab = A + (size_t)bin * CAPB;
    for (int p = t; p < len; p += 256) {
        uint2 rec = Ab[p];
        atomicAdd(&cnt[rec.x >> 19], 1);
        atomicAdd(&wsum[rec.x >> 19], __uint_as_float(rec.y));
    }
    const int ovn = min(*ovcur, OVCAP);
    for (int i = t; i < ovn; i += 256) {
        int cflat = ovf[3 * i];
        if ((cflat >> 10) == bin) {
            atomicAdd(&cnt[cflat & 1023], 1);
            atomicAdd(&wsum[cflat & 1023], __int_as_float(ovf[3 * i + 2]));
        }
    }
    __syncthreads();
    // scan: thread t owns nodes 4t..4t+3
    int c0 = cnt[4 * t], c1 = cnt[4 * t + 1], c2 = cnt[4 * t + 2], c3 = cnt[4 * t + 3];
    int vsum = c0 + c1 + c2 + c3;
    sh[t] = vsum;
    __syncthreads();
    for (int d = 1; d < 256; d <<= 1) {
        int add = (t >= d) ? sh[t - d] : 0;
        __syncthreads();
        sh[t] += add;
        __syncthreads();
    }
    const int base = bin * CAPB;
    const int lim = base + CAPB;
    int p0 = base + sh[t] - vsum;
    int p1 = p0 + c0, p2 = p1 + c1, p3 = p2 + c2;
    pos[4 * t] = p0; pos[4 * t + 1] = p1; pos[4 * t + 2] = p2; pos[4 * t + 3] = p3;
    int starts[4] = {p0, p1, p2, p3};
    int cs[4] = {c0, c1, c2, c3};
#pragma unroll
    for (int j = 0; j < 4; ++j) {
        int cl = 4 * t + j;
        int node = (bin << 10) + cl;
        if (node < NTOT) {
            nodeoff[node] = make_int2(starts[j], cs[j]);
            float dg = wsum[cl];
            dinv[node] = (dg > 0.0f) ? rsqrtf(dg) : 0.0f;
        }
    }
    __syncthreads();
    for (int p = t; p < len; p += 256) {
        uint2 rec = Ab[p];
        int s = atomicAdd(&pos[rec.x >> 19], 1);
        if (s < lim) C[s] = make_uint2(rec.x & 0x7FFFFu, rec.y);
    }
    for (int i = t; i < ovn; i += 256) {
        int cflat = ovf[3 * i];
        if ((cflat >> 10) == bin) {
            int s = atomicAdd(&pos[cflat & 1023], 1);
            if (s < lim) C[s] = make_uint2((unsigned)ovf[3 * i + 1], (unsigned)ovf[3 * i + 2]);
        }
    }
}

// ---------------- prep: W fp32 [mp][k][n] -> bf16 transposed wT [mp][n][k] ----------------
__global__ __launch_bounds__(256) void prep_w_kernel(const float* __restrict__ W,
                                                     unsigned short* __restrict__ wT) {
    int idx = blockIdx.x * 256 + threadIdx.x;
    if (idx >= NMP * D * D) return;
    int mp = idx >> 12, rem = idx & 4095;
    int k = rem >> 6, n = rem & 63;
    wT[(mp * D + n) * D + k] = f2bf(W[idx]);
}

// ---------------- MFMA GEMM (operand-swapped): lane's 4 accs are contiguous in h ----------------
__global__ __launch_bounds__(256) void gemm_kernel(const float* __restrict__ x,
                                                   const unsigned short* __restrict__ wT,
                                                   const float* __restrict__ dinv,
                                                   unsigned short* __restrict__ h) {
    const int wave = threadIdx.x >> 6;
    const int lane = threadIdx.x & 63;
    const int rowbase = (blockIdx.x * 4 + wave) * 16;
    if (rowbase >= NNODES) return;
    const int m = lane & 15;
    const int q = lane >> 4;
    const float4* xr = (const float4*)(x + (size_t)(rowbase + m) * D);
    bf16x8 a[2];
#pragma unroll
    for (int kc = 0; kc < 2; ++kc) {
        float4 x0 = xr[kc * 8 + q * 2];
        float4 x1 = xr[kc * 8 + q * 2 + 1];
        a[kc][0] = f2bf(x0.x); a[kc][1] = f2bf(x0.y);
        a[kc][2] = f2bf(x0.z); a[kc][3] = f2bf(x0.w);
        a[kc][4] = f2bf(x1.x); a[kc][5] = f2bf(x1.y);
        a[kc][6] = f2bf(x1.z); a[kc][7] = f2bf(x1.w);
    }
#pragma unroll
    for (int mp = 0; mp < NMP; ++mp) {
        float dv = dinv[mp * NNODES + rowbase + m];   // per x-row scale
#pragma unroll
        for (int nt = 0; nt < 4; ++nt) {
            const bf16x8* bp = (const bf16x8*)(wT + (size_t)(mp * D + nt * 16 + m) * D);
            bf16x8 b0 = bp[q];       // k = q*8 .. +7
            bf16x8 b1 = bp[4 + q];   // k = 32 + q*8 .. +7
            floatx4 acc = {0.f, 0.f, 0.f, 0.f};
            acc = __builtin_amdgcn_mfma_f32_16x16x32_bf16(b0, a[0], acc, 0, 0, 0);
            acc = __builtin_amdgcn_mfma_f32_16x16x32_bf16(b1, a[1], acc, 0, 0, 0);
            unsigned v0 = (unsigned)f2bf(acc[0] * dv) | ((unsigned)f2bf(acc[1] * dv) << 16);
            unsigned v1 = (unsigned)f2bf(acc[2] * dv) | ((unsigned)f2bf(acc[3] * dv) << 16);
            *(uint2*)(h + ((size_t)mp * NNODES + rowbase + m) * D + nt * 16 + q * 4) =
                make_uint2(v0, v1);
        }
    }
}

// ---------------- gather: 2 nodes/wave, 4 edge slots/node, depth-2 pipeline ----------------
// 32 lanes per node: g = edge slot (0..3), f = feature chunk (8 x 16B = 128B bf16 row).
// Record prefetched 2 rounds ahead; its h-row 1 round ahead -> dependent chain off critical path.
__global__ __launch_bounds__(256) void gather_kernel(const int2* __restrict__ nodeoff,
                                                     const uint2* __restrict__ dense,
                                                     const unsigned short* __restrict__ h,
                                                     const float* __restrict__ dinv,
                                                     float* __restrict__ out) {
    const int tid = threadIdx.x;
    const int wave = tid >> 6, lane = tid & 63;
    const int sub = lane >> 5;     // node within wave (0..1)
    const int g = (lane >> 3) & 3; // edge slot (0..3)
    const int f = lane & 7;        // feature chunk (8 bf16 = 16 B)
    const int w = blockIdx.x * 8 + wave * 2 + sub;   // NTOT = 8*37500
    int2 off = nodeoff[w];
    const int start = off.x, end = off.x + off.y;
    const uint4* hp = (const uint4*)h;
    float acc[8] = {0, 0, 0, 0, 0, 0, 0, 0};
    if (end > start) {
        const int last = end - 1;
        uint2 prA = dense[min(start + g, last)];
        uint2 prB = dense[min(start + 4 + g, last)];
        uint4 hvA = hp[(size_t)prA.x * 8 + f];
        for (int p = start; p < end; p += 4) {
            uint2 prC = dense[min(p + 8 + g, last)];
            uint4 hvB = hp[(size_t)prB.x * 8 + f];   // addr ready (record loaded 2 rounds ago)
            float wgt = (p + g < end) ? __uint_as_float(prA.y) : 0.0f;
            acc[0] += wgt * bf2f_lo(hvA.x); acc[1] += wgt * bf2f_hi(hvA.x);
            acc[2] += wgt * bf2f_lo(hvA.y); acc[3] += wgt * bf2f_hi(hvA.y);
            acc[4] += wgt * bf2f_lo(hvA.z); acc[5] += wgt * bf2f_hi(hvA.z);
            acc[6] += wgt * bf2f_lo(hvA.w); acc[7] += wgt * bf2f_hi(hvA.w);
            prA = prB; hvA = hvB; prB = prC;
        }
    }
#pragma unroll
    for (int j = 0; j < 8; ++j) {                   // reduce across 4 edge slots
        acc[j] += __shfl_xor(acc[j], 8);
        acc[j] += __shfl_xor(acc[j], 16);
    }
    float dv = dinv[w];
    if (g < 2) {
        float4 o = g ? make_float4(acc[4], acc[5], acc[6], acc[7])
                     : make_float4(acc[0], acc[1], acc[2], acc[3]);
        o.x = fmaxf(o.x * dv, 0.0f);
        o.y = fmaxf(o.y * dv, 0.0f);
        o.z = fmaxf(o.z * dv, 0.0f);
        o.w = fmaxf(o.w * dv, 0.0f);
        ((float4*)out)[(size_t)w * 16 + f * 2 + g] = o;   // 256 B contiguous per node
    }
}

extern "C" void kernel_launch(void* const* d_in, const int* in_sizes, int n_in,
                              void* d_out, int out_size, void* d_ws, size_t ws_size,
                              hipStream_t stream) {
    const float* x  = (const float*)d_in[0];   // [N, 64]
    const float* W  = (const float*)d_in[1];   // [3, 64, 64]
    const int*   ei = (const int*)d_in[2];     // [3, 2, E]
    const float* ew = (const float*)d_in[3];   // [3, E]
    float* out = (float*)d_out;                // [3, N, 64]

    // layout (bytes). A (25.65 MB) is dead after compact2; h (38.4 MB) overlays it.
    char* ws = (char*)d_ws;
    uint2* A           = (uint2*)(ws + 0);                     // 293*10944*8 = 25,652,736 B
    unsigned short* h  = (unsigned short*)(ws + 0);            // 38,400,000 B (overlays A)
    uint2* C           = (uint2*)(ws + 38400000);              // 25,652,736 B
    int2*  nodeoff     = (int2*)(ws + 64052736);               // 2,400,000 B
    float* dinv        = (float*)(ws + 66452736);              // 1,200,000 B
    unsigned short* wT = (unsigned short*)(ws + 67652736);     // 24,576 B
    int*   gcur        = (int*)(ws + 67677312);                // 1,172 B
    int*   ovcur       = (int*)(ws + 67678484);                // 4 B (adjacent to gcur)
    int*   ovf         = (int*)(ws + 67678488);                // 1,572,864 B -> ends ~69.25 MB

    hipMemsetAsync(gcur, 0, 1176, stream);     // gcur + ovcur

    split_kernel<<<dim3((NEDGES + T1 - 1) / T1, NMP), 512, 0, stream>>>(ei, ew, gcur,
                                                                        ovcur, ovf, A);
    compact2_kernel<<<NBIN, 256, 0, stream>>>(gcur, A, ovcur, ovf, C, nodeoff, dinv);
    prep_w_kernel<<<(NMP * D * D + 255) / 256, 256, 0, stream>>>(W, wT);
    gemm_kernel<<<(NNODES / 16 + 3) / 4, 256, 0, stream>>>(x, wT, dinv, h);
    gather_kernel<<<NTOT / 8, 256, 0, stream>>>(nodeoff, C, h, dinv, out);
}